// Round 1
// baseline (1226.696 us; speedup 1.0000x reference)
//
#include <hip/hip_runtime.h>

#define N_NODES 50000
#define N_EDGES 640000
#define D 128          // D_IN == D_OUT
#define NB 8           // num bases
#define ROWS_PER_BLOCK 32

__device__ __forceinline__ void fma4(float4& acc, float s, const float4& v) {
    acc.x += s * v.x; acc.y += s * v.y; acc.z += s * v.z; acc.w += s * v.w;
}

// W[i][o] = sum_b comp[b] * bases[b][i][o]   (16384 floats = 4096 float4)
__global__ __launch_bounds__(256)
void compute_W_kernel(const float* __restrict__ bases,
                      const float* __restrict__ comp,
                      float* __restrict__ W) {
    int idx = blockIdx.x * 256 + threadIdx.x;   // float4 index
    if (idx >= D * D / 4) return;
    const float4* b4 = (const float4*)bases;
    float4 acc = make_float4(0.f, 0.f, 0.f, 0.f);
#pragma unroll
    for (int b = 0; b < NB; ++b)
        fma4(acc, comp[b], b4[b * (D * D / 4) + idx]);
    ((float4*)W)[idx] = acc;
}

// y = x @ W ; out = x @ root + bias   (one pass over x)
__global__ __launch_bounds__(256)
void gemm_dual_kernel(const float* __restrict__ x,
                      const float* __restrict__ W,
                      const float* __restrict__ root,
                      const float* __restrict__ bias,
                      float* __restrict__ y,
                      float* __restrict__ out) {
    __shared__ float4 xs[ROWS_PER_BLOCK * 32];   // 32 rows x 128 f32 = 16 KB
    const int row0 = blockIdx.x * ROWS_PER_BLOCK;
    const int tid  = threadIdx.x;

    const float4* x4 = (const float4*)x;
#pragma unroll
    for (int l = 0; l < 4; ++l) {
        int li = tid + l * 256;                  // 0..1023
        int r  = row0 + (li >> 5);
        if (r < N_NODES) xs[li] = x4[(size_t)r * 32 + (li & 31)];
    }
    __syncthreads();

    const int o4 = tid & 31;                     // output float4 column 0..31
    const int ng = tid >> 5;                     // node group 0..7 (4 nodes each)
    const float4* W4 = (const float4*)W;
    const float4* R4 = (const float4*)root;

    float4 accW[4], accR[4];
#pragma unroll
    for (int n = 0; n < 4; ++n) {
        accW[n] = make_float4(0.f, 0.f, 0.f, 0.f);
        accR[n] = make_float4(0.f, 0.f, 0.f, 0.f);
    }

#pragma unroll 4
    for (int i4 = 0; i4 < 32; ++i4) {            // K in chunks of 4
        float4 w[4], r[4];
#pragma unroll
        for (int k = 0; k < 4; ++k) {
            w[k] = W4[(i4 * 4 + k) * 32 + o4];
            r[k] = R4[(i4 * 4 + k) * 32 + o4];
        }
#pragma unroll
        for (int n = 0; n < 4; ++n) {
            float4 a = xs[(ng * 4 + n) * 32 + i4];
            fma4(accW[n], a.x, w[0]); fma4(accW[n], a.y, w[1]);
            fma4(accW[n], a.z, w[2]); fma4(accW[n], a.w, w[3]);
            fma4(accR[n], a.x, r[0]); fma4(accR[n], a.y, r[1]);
            fma4(accR[n], a.z, r[2]); fma4(accR[n], a.w, r[3]);
        }
    }

    const float4 bv = ((const float4*)bias)[o4];
    float4* y4 = (float4*)y;
    float4* o4p = (float4*)out;
#pragma unroll
    for (int n = 0; n < 4; ++n) {
        int rrow = row0 + ng * 4 + n;
        if (rrow < N_NODES) {
            y4[(size_t)rrow * 32 + o4] = accW[n];
            float4 ov = accR[n];
            ov.x += bv.x; ov.y += bv.y; ov.z += bv.z; ov.w += bv.w;
            o4p[(size_t)rrow * 32 + o4] = ov;
        }
    }
}

// out[dst] += y[src]  — 32 threads per edge, float4 per thread, 4 atomics
__global__ __launch_bounds__(256)
void scatter_kernel(const int* __restrict__ eidx,
                    const float* __restrict__ y,
                    float* __restrict__ out) {
    int tid = blockIdx.x * 256 + threadIdx.x;    // 20.48M total, fits int
    int e = tid >> 5;
    int q = tid & 31;
    if (e >= N_EDGES) return;
    int src = eidx[e];
    int dst = eidx[N_EDGES + e];
    float4 v = ((const float4*)y)[(size_t)src * 32 + q];
    float* op = out + (size_t)dst * 128 + q * 4;
    atomicAdd(op + 0, v.x);
    atomicAdd(op + 1, v.y);
    atomicAdd(op + 2, v.z);
    atomicAdd(op + 3, v.w);
}

extern "C" void kernel_launch(void* const* d_in, const int* in_sizes, int n_in,
                              void* d_out, int out_size, void* d_ws, size_t ws_size,
                              hipStream_t stream) {
    const float* x     = (const float*)d_in[0];
    const int*   eidx  = (const int*)d_in[1];
    const float* bases = (const float*)d_in[2];
    const float* comp  = (const float*)d_in[3];
    const float* root  = (const float*)d_in[4];
    const float* bias  = (const float*)d_in[5];
    float* out = (float*)d_out;

    float* y = (float*)d_ws;                                   // N*128 f32 = 25.6 MB
    float* W = (float*)((char*)d_ws + (size_t)N_NODES * D * sizeof(float));

    compute_W_kernel<<<16, 256, 0, stream>>>(bases, comp, W);
    gemm_dual_kernel<<<(N_NODES + ROWS_PER_BLOCK - 1) / ROWS_PER_BLOCK, 256, 0, stream>>>(
        x, W, root, bias, y, out);
    scatter_kernel<<<(N_EDGES * 32) / 256, 256, 0, stream>>>(eidx, y, out);
}

// Round 2
// 248.863 us; speedup vs baseline: 4.9292x; 4.9292x over previous
//
#include <hip/hip_runtime.h>

#define N_NODES 50000
#define N_EDGES 640000
#define D 128          // D_IN == D_OUT
#define NB 8           // num bases
#define ROWS_PER_BLOCK 32
#define PAD 64         // bucket slots per dst node (mean degree 12.8)

__device__ __forceinline__ void fma4(float4& acc, float s, const float4& v) {
    acc.x += s * v.x; acc.y += s * v.y; acc.z += s * v.z; acc.w += s * v.w;
}
__device__ __forceinline__ void add4(float4& acc, const float4& v) {
    acc.x += v.x; acc.y += v.y; acc.z += v.z; acc.w += v.w;
}

// W[i][o] = sum_b comp[b] * bases[b][i][o]
__global__ __launch_bounds__(256)
void compute_W_kernel(const float* __restrict__ bases,
                      const float* __restrict__ comp,
                      float* __restrict__ W) {
    int idx = blockIdx.x * 256 + threadIdx.x;   // float4 index
    if (idx >= D * D / 4) return;
    const float4* b4 = (const float4*)bases;
    float4 acc = make_float4(0.f, 0.f, 0.f, 0.f);
#pragma unroll
    for (int b = 0; b < NB; ++b)
        fma4(acc, comp[b], b4[b * (D * D / 4) + idx]);
    ((float4*)W)[idx] = acc;
}

__global__ __launch_bounds__(256)
void zero_cnt_kernel(int* __restrict__ cnt) {
    int i = blockIdx.x * 256 + threadIdx.x;
    if (i < N_NODES) cnt[i] = 0;
}

// y = x @ W ; out = x @ root + bias   (one pass over x)
__global__ __launch_bounds__(256)
void gemm_dual_kernel(const float* __restrict__ x,
                      const float* __restrict__ W,
                      const float* __restrict__ root,
                      const float* __restrict__ bias,
                      float* __restrict__ y,
                      float* __restrict__ out) {
    __shared__ float4 xs[ROWS_PER_BLOCK * 32];   // 32 rows x 128 f32 = 16 KB
    const int row0 = blockIdx.x * ROWS_PER_BLOCK;
    const int tid  = threadIdx.x;

    const float4* x4 = (const float4*)x;
#pragma unroll
    for (int l = 0; l < 4; ++l) {
        int li = tid + l * 256;                  // 0..1023
        int r  = row0 + (li >> 5);
        if (r < N_NODES) xs[li] = x4[(size_t)r * 32 + (li & 31)];
    }
    __syncthreads();

    const int o4 = tid & 31;                     // output float4 column 0..31
    const int ng = tid >> 5;                     // node group 0..7 (4 nodes each)
    const float4* W4 = (const float4*)W;
    const float4* R4 = (const float4*)root;

    float4 accW[4], accR[4];
#pragma unroll
    for (int n = 0; n < 4; ++n) {
        accW[n] = make_float4(0.f, 0.f, 0.f, 0.f);
        accR[n] = make_float4(0.f, 0.f, 0.f, 0.f);
    }

#pragma unroll 4
    for (int i4 = 0; i4 < 32; ++i4) {            // K in chunks of 4
        float4 w[4], r[4];
#pragma unroll
        for (int k = 0; k < 4; ++k) {
            w[k] = W4[(i4 * 4 + k) * 32 + o4];
            r[k] = R4[(i4 * 4 + k) * 32 + o4];
        }
#pragma unroll
        for (int n = 0; n < 4; ++n) {
            float4 a = xs[(ng * 4 + n) * 32 + i4];
            fma4(accW[n], a.x, w[0]); fma4(accW[n], a.y, w[1]);
            fma4(accW[n], a.z, w[2]); fma4(accW[n], a.w, w[3]);
            fma4(accR[n], a.x, r[0]); fma4(accR[n], a.y, r[1]);
            fma4(accR[n], a.z, r[2]); fma4(accR[n], a.w, r[3]);
        }
    }

    const float4 bv = ((const float4*)bias)[o4];
    float4* y4 = (float4*)y;
    float4* o4p = (float4*)out;
#pragma unroll
    for (int n = 0; n < 4; ++n) {
        int rrow = row0 + ng * 4 + n;
        if (rrow < N_NODES) {
            y4[(size_t)rrow * 32 + o4] = accW[n];
            float4 ov = accR[n];
            ov.x += bv.x; ov.y += bv.y; ov.z += bv.z; ov.w += bv.w;
            o4p[(size_t)rrow * 32 + o4] = ov;
        }
    }
}

// For each edge: one int atomic to place src into dst's bucket.
// Overflow (prob ~1e-24) falls back to direct float atomics — correct, never hot.
__global__ __launch_bounds__(256)
void bucket_kernel(const int* __restrict__ eidx,
                   const float* __restrict__ y,
                   float* __restrict__ out,
                   int* __restrict__ cnt,
                   int* __restrict__ bucket) {
    int e = blockIdx.x * 256 + threadIdx.x;
    if (e >= N_EDGES) return;
    int src = eidx[e];
    int dst = eidx[N_EDGES + e];
    int pos = atomicAdd(&cnt[dst], 1);
    if (pos < PAD) {
        bucket[(size_t)dst * PAD + pos] = src;
    } else {
        const float* yr = y + (size_t)src * D;
        float* op = out + (size_t)dst * D;
        for (int q = 0; q < D; ++q) atomicAdd(op + q, yr[q]);
    }
}

// 32 lanes per node: lane q owns float4 column q. Sum bucket rows, one write.
__global__ __launch_bounds__(256)
void gather_kernel(const int* __restrict__ cnt,
                   const int* __restrict__ bucket,
                   const float* __restrict__ y,
                   float* __restrict__ out) {
    int g = blockIdx.x * 8 + (threadIdx.x >> 5);   // node, 8 per block
    int q = threadIdx.x & 31;
    if (g >= N_NODES) return;
    int c = cnt[g];
    if (c > PAD) c = PAD;
    const int* b = bucket + (size_t)g * PAD;
    const float4* y4 = (const float4*)y;
    float4 acc = make_float4(0.f, 0.f, 0.f, 0.f);
    int i = 0;
    for (; i + 4 <= c; i += 4) {
        int4 s = *(const int4*)(b + i);            // 16B-aligned (PAD%4==0)
        float4 v0 = y4[(size_t)s.x * 32 + q];
        float4 v1 = y4[(size_t)s.y * 32 + q];
        float4 v2 = y4[(size_t)s.z * 32 + q];
        float4 v3 = y4[(size_t)s.w * 32 + q];
        add4(acc, v0); add4(acc, v1); add4(acc, v2); add4(acc, v3);
    }
    for (; i < c; ++i) {
        int s = b[i];
        add4(acc, y4[(size_t)s * 32 + q]);
    }
    float4* op = (float4*)out + (size_t)g * 32 + q;
    float4 cur = *op;
    add4(cur, acc);
    *op = cur;
}

extern "C" void kernel_launch(void* const* d_in, const int* in_sizes, int n_in,
                              void* d_out, int out_size, void* d_ws, size_t ws_size,
                              hipStream_t stream) {
    const float* x     = (const float*)d_in[0];
    const int*   eidx  = (const int*)d_in[1];
    const float* bases = (const float*)d_in[2];
    const float* comp  = (const float*)d_in[3];
    const float* root  = (const float*)d_in[4];
    const float* bias  = (const float*)d_in[5];
    float* out = (float*)d_out;

    char* ws = (char*)d_ws;
    float* y      = (float*)ws;                                    // 25,600,000 B
    float* W      = (float*)(ws + (size_t)N_NODES * D * 4);        // 65,536 B
    int*   cnt    = (int*)(ws + (size_t)N_NODES * D * 4 + D * D * 4);
    int*   bucket = cnt + N_NODES;                                 // 12,800,000 B

    zero_cnt_kernel<<<(N_NODES + 255) / 256, 256, 0, stream>>>(cnt);
    compute_W_kernel<<<16, 256, 0, stream>>>(bases, comp, W);
    gemm_dual_kernel<<<(N_NODES + ROWS_PER_BLOCK - 1) / ROWS_PER_BLOCK, 256, 0, stream>>>(
        x, W, root, bias, y, out);
    bucket_kernel<<<(N_EDGES + 255) / 256, 256, 0, stream>>>(eidx, y, out, cnt, bucket);
    gather_kernel<<<(N_NODES + 7) / 8, 256, 0, stream>>>(cnt, bucket, y, out);
}

// Round 3
// 183.479 us; speedup vs baseline: 6.6858x; 1.3564x over previous
//
#include <hip/hip_runtime.h>

#define N_NODES 50000
#define N_EDGES 640000
#define D 128          // D_IN == D_OUT
#define NB 8           // num bases
#define PAD 64         // bucket slots per dst node (mean degree 12.8)
#define BM 64          // GEMM rows per block
#define LDA 136        // LDS A row stride in halfs (128 + 8 pad -> 2-way conflicts only)

typedef _Float16 half_t;
typedef __attribute__((ext_vector_type(8))) _Float16 half8;
typedef __attribute__((ext_vector_type(4))) float f32x4;

__device__ __forceinline__ void add4(float4& acc, const float4& v) {
    acc.x += v.x; acc.y += v.y; acc.z += v.z; acc.w += v.w;
}

// Wt[o][i] = (half) sum_b comp[b] * bases[b][i][o]   (transposed, fp16)
// Rt[o][i] = (half) root[i][o]
__global__ __launch_bounds__(256)
void compute_Wt_kernel(const float* __restrict__ bases,
                       const float* __restrict__ comp,
                       const float* __restrict__ root,
                       half_t* __restrict__ Wt,
                       half_t* __restrict__ Rt) {
    int idx = blockIdx.x * 256 + threadIdx.x;    // 0..16383
    if (idx >= D * D) return;
    int i = idx >> 7, o = idx & 127;             // coalesced read over o
    float acc = 0.f;
#pragma unroll
    for (int b = 0; b < NB; ++b)
        acc += comp[b] * bases[((size_t)b * D + i) * D + o];
    Wt[o * D + i] = (half_t)acc;
    Rt[o * D + i] = (half_t)root[idx];
}

__global__ __launch_bounds__(256)
void zero_cnt_kernel(int* __restrict__ cnt) {
    int i = blockIdx.x * 256 + threadIdx.x;
    if (i < N_NODES) cnt[i] = 0;
}

// y(half) = x @ W ; out(f32) = x @ root + bias — MFMA 16x16x32 fp16
__global__ __launch_bounds__(256)
void gemm_mfma_kernel(const float* __restrict__ x,
                      const half_t* __restrict__ Wt,   // [n][k]
                      const half_t* __restrict__ Rt,   // [n][k]
                      const float* __restrict__ bias,
                      half_t* __restrict__ y,
                      float* __restrict__ out) {
    __shared__ __align__(16) half_t As[BM * LDA];
    const int row0 = blockIdx.x * BM;
    const int tid  = threadIdx.x;

    // stage 64 rows of x, fp32 -> fp16, into LDS
    {
        int r  = tid >> 2;                 // 0..63
        int cc = (tid & 3) * 32;           // col chunk
        if (row0 + r < N_NODES) {
            const float4* x4 = (const float4*)x;
            size_t base = (size_t)(row0 + r) * 32 + (cc >> 2);
#pragma unroll
            for (int u = 0; u < 4; ++u) {
                float4 v0 = x4[base + 2 * u];
                float4 v1 = x4[base + 2 * u + 1];
                half8 h;
                h[0] = (half_t)v0.x; h[1] = (half_t)v0.y;
                h[2] = (half_t)v0.z; h[3] = (half_t)v0.w;
                h[4] = (half_t)v1.x; h[5] = (half_t)v1.y;
                h[6] = (half_t)v1.z; h[7] = (half_t)v1.w;
                *(half8*)&As[r * LDA + cc + u * 8] = h;
            }
        }
    }
    __syncthreads();

    const int wave = tid >> 6;           // 0..3, 16-row strip each
    const int lane = tid & 63;
    const int m    = lane & 15;
    const int quad = lane >> 4;

    // A fragments: A[m][k], m = lane&15, k = quad*8 + j   (4 K-steps of 32)
    half8 a[4];
#pragma unroll
    for (int kk = 0; kk < 4; ++kk)
        a[kk] = *(const half8*)&As[(wave * 16 + m) * LDA + kk * 32 + quad * 8];

    f32x4 accW[8], accR[8];
#pragma unroll
    for (int nt = 0; nt < 8; ++nt) {
        accW[nt] = (f32x4){0.f, 0.f, 0.f, 0.f};
        accR[nt] = (f32x4){0.f, 0.f, 0.f, 0.f};
    }

#pragma unroll
    for (int nt = 0; nt < 8; ++nt) {
        // B frags: B[k][n], n = lane&15, k = quad*8 + j; Wt row-major [n][k]
        const half_t* wp = Wt + (nt * 16 + m) * D + quad * 8;
        const half_t* rp = Rt + (nt * 16 + m) * D + quad * 8;
        half8 bw[4], br[4];
#pragma unroll
        for (int kk = 0; kk < 4; ++kk) {
            bw[kk] = *(const half8*)(wp + kk * 32);
            br[kk] = *(const half8*)(rp + kk * 32);
        }
#pragma unroll
        for (int kk = 0; kk < 4; ++kk) {
            accW[nt] = __builtin_amdgcn_mfma_f32_16x16x32_f16(a[kk], bw[kk], accW[nt], 0, 0, 0);
            accR[nt] = __builtin_amdgcn_mfma_f32_16x16x32_f16(a[kk], br[kk], accR[nt], 0, 0, 0);
        }
    }

    // C/D layout: col = lane&15, row = quad*4 + reg
#pragma unroll
    for (int nt = 0; nt < 8; ++nt) {
        int col = nt * 16 + m;
        float bb = bias[col];
#pragma unroll
        for (int r = 0; r < 4; ++r) {
            int row = row0 + wave * 16 + quad * 4 + r;
            if (row < N_NODES) {
                y[(size_t)row * D + col]   = (half_t)accW[nt][r];
                out[(size_t)row * D + col] = accR[nt][r] + bb;
            }
        }
    }
}

// one int atomic per edge to place src into dst's bucket
__global__ __launch_bounds__(256)
void bucket_kernel(const int* __restrict__ eidx,
                   const half_t* __restrict__ y,
                   float* __restrict__ out,
                   int* __restrict__ cnt,
                   int* __restrict__ bucket) {
    int e = blockIdx.x * 256 + threadIdx.x;
    if (e >= N_EDGES) return;
    int src = eidx[e];
    int dst = eidx[N_EDGES + e];
    int pos = atomicAdd(&cnt[dst], 1);
    if (pos < PAD) {
        bucket[(size_t)dst * PAD + pos] = src;
    } else {   // ~never (P < 1e-20); correct fallback
        const half_t* yr = y + (size_t)src * D;
        float* op = out + (size_t)dst * D;
        for (int q = 0; q < D; ++q) atomicAdd(op + q, (float)yr[q]);
    }
}

// 16 lanes per node: lane q owns 8 cols (16 B of half y). One RMW of out.
__global__ __launch_bounds__(256)
void gather_kernel(const int* __restrict__ cnt,
                   const int* __restrict__ bucket,
                   const half_t* __restrict__ y,
                   float* __restrict__ out) {
    int node = blockIdx.x * 16 + (threadIdx.x >> 4);
    int q = threadIdx.x & 15;
    if (node >= N_NODES) return;
    int c = cnt[node];
    if (c > PAD) c = PAD;
    const int* b = bucket + (size_t)node * PAD;
    float acc[8] = {0.f, 0.f, 0.f, 0.f, 0.f, 0.f, 0.f, 0.f};
    int i = 0;
    for (; i + 4 <= c; i += 4) {
        int4 s = *(const int4*)(b + i);
        half8 v0 = *(const half8*)(y + (size_t)s.x * D + q * 8);
        half8 v1 = *(const half8*)(y + (size_t)s.y * D + q * 8);
        half8 v2 = *(const half8*)(y + (size_t)s.z * D + q * 8);
        half8 v3 = *(const half8*)(y + (size_t)s.w * D + q * 8);
#pragma unroll
        for (int j = 0; j < 8; ++j)
            acc[j] += (float)v0[j] + (float)v1[j] + (float)v2[j] + (float)v3[j];
    }
    for (; i < c; ++i) {
        half8 v = *(const half8*)(y + (size_t)b[i] * D + q * 8);
#pragma unroll
        for (int j = 0; j < 8; ++j) acc[j] += (float)v[j];
    }
    float4* op = (float4*)(out + (size_t)node * D + q * 8);
    float4 o0 = op[0], o1 = op[1];
    o0.x += acc[0]; o0.y += acc[1]; o0.z += acc[2]; o0.w += acc[3];
    o1.x += acc[4]; o1.y += acc[5]; o1.z += acc[6]; o1.w += acc[7];
    op[0] = o0; op[1] = o1;
}

extern "C" void kernel_launch(void* const* d_in, const int* in_sizes, int n_in,
                              void* d_out, int out_size, void* d_ws, size_t ws_size,
                              hipStream_t stream) {
    const float* x     = (const float*)d_in[0];
    const int*   eidx  = (const int*)d_in[1];
    const float* bases = (const float*)d_in[2];
    const float* comp  = (const float*)d_in[3];
    const float* root  = (const float*)d_in[4];
    const float* bias  = (const float*)d_in[5];
    float* out = (float*)d_out;

    char* ws = (char*)d_ws;
    half_t* y      = (half_t*)ws;                              // 12,800,000 B
    half_t* Wt     = (half_t*)(ws + 12800000);                 // 32,768 B
    half_t* Rt     = (half_t*)(ws + 12832768);                 // 32,768 B
    int*    cnt    = (int*)(ws + 12865536);                    // 200,000 B
    int*    bucket = (int*)(ws + 13065536);                    // 12,800,000 B

    zero_cnt_kernel<<<(N_NODES + 255) / 256, 256, 0, stream>>>(cnt);
    compute_Wt_kernel<<<(D * D + 255) / 256, 256, 0, stream>>>(bases, comp, root, Wt, Rt);
    gemm_mfma_kernel<<<(N_NODES + BM - 1) / BM, 256, 0, stream>>>(x, Wt, Rt, bias, y, out);
    bucket_kernel<<<(N_EDGES + 255) / 256, 256, 0, stream>>>(eidx, y, out, cnt, bucket);
    gather_kernel<<<(N_NODES + 15) / 16, 256, 0, stream>>>(cnt, bucket, y, out);
}